// Round 3
// baseline (3393.930 us; speedup 1.0000x reference)
//
#include <hip/hip_runtime.h>
#include <math.h>

#define BB   128
#define TT   25
#define RR   100
#define DD   512
#define VV   10000
#define NG   2048
#define PAD  8

typedef short bf8   __attribute__((ext_vector_type(8)));
typedef float f32x4 __attribute__((ext_vector_type(4)));

__device__ __forceinline__ float sigm(float x) { return 1.f / (1.f + expf(-x)); }

__device__ __forceinline__ short f2bf(float f) {
  unsigned u = __float_as_uint(f);
  u += 0x7fffu + ((u >> 16) & 1u);
  return (short)(u >> 16);
}
__device__ __forceinline__ float bf2f(short h) {
  return __uint_as_float(((unsigned)(unsigned short)h) << 16);
}

// ============ init: h0 -> CCH1[h0], h1 -> CCH0[h1], c0/c1 f32 ============
__global__ __launch_bounds__(256) void k_init(const float* __restrict__ ihs,
                                              short* __restrict__ CCH0,
                                              short* __restrict__ CCH1,
                                              float* __restrict__ C0,
                                              float* __restrict__ C1) {
  int idx = blockIdx.x * 256 + threadIdx.x;     // < 262144
  int s = idx >> 17, r = idx & 131071, b = r >> 10, j = r & 1023;
  float v = ihs[idx];
  if (s == 0) {
    if (j < 512) CCH1[b * 1536 + j] = f2bf(v);
    else         C0[b * 512 + (j - 512)] = v;
  } else {
    if (j < 512) CCH0[b * 1536 + 1024 + j] = f2bf(v);
    else         C1[b * 512 + (j - 512)] = v;
  }
}

// ============ cnn pooled ============
__global__ __launch_bounds__(256) void k_pool(const float* __restrict__ feat,
                                              float* __restrict__ pool) {
  int idx = blockIdx.x * 256 + threadIdx.x;     // < 65536
  int b = idx >> 9, d = idx & 511;
  float m = -3.4e38f;
  #pragma unroll
  for (int r = 0; r < 10; r++)
    m = fmaxf(m, feat[((size_t)b * RR + r) * 512 + d]);
  pool[idx] = m;
}

// ============ Xin (3200 x 1024 bf16), row m = t*128+b ============
__global__ __launch_bounds__(256) void k_xin(const int* __restrict__ tok,
                                             const float* __restrict__ emb,
                                             const float* __restrict__ pool,
                                             short* __restrict__ xin) {
  int idx = blockIdx.x * 256 + threadIdx.x;     // < 3,276,800
  int m = idx >> 10, k = idx & 1023;
  int t = m >> 7, b = m & 127;
  float v;
  if (k < 512) v = emb[(size_t)tok[b * TT + t] * 512 + k];
  else         v = pool[b * 512 + (k - 512)];
  xin[idx] = f2bf(v);
}

// ====== transpose f32 (KxNsrc) -> bf16 (N x K); gi: out row n <- col (n&3)*512+(n>>2)
// here write loop maps source col c -> out row ((c&511)*4 + (c>>9))
__global__ __launch_bounds__(256) void k_transpose(const float* __restrict__ in,
                                                   short* __restrict__ out,
                                                   int K, int Nsrc, int gi) {
  __shared__ float tile[32][33];
  int kt = blockIdx.y * 32, ct = blockIdx.x * 32;
  int tx = threadIdx.x & 31, ty = threadIdx.x >> 5;
  #pragma unroll
  for (int i = 0; i < 32; i += 8) {
    int k = kt + ty + i, c = ct + tx;
    tile[ty + i][tx] = (c < Nsrc) ? in[(size_t)k * Nsrc + c] : 0.f;
  }
  __syncthreads();
  #pragma unroll
  for (int i = 0; i < 32; i += 8) {
    int c = ct + ty + i;
    if (c < Nsrc) {
      int n = gi ? ((c & 511) * 4 + (c >> 9)) : c;
      out[(size_t)n * K + kt + tx] = f2bf(tile[tx][ty + i]);
    }
  }
}

// ====== transpose f32 (1024 x 100) -> f32 aWT (100 x 1024) ======
__global__ __launch_bounds__(256) void k_transf(const float* __restrict__ in,
                                                float* __restrict__ out) {
  __shared__ float tile[32][33];
  int kt = blockIdx.y * 32, ct = blockIdx.x * 32;
  int tx = threadIdx.x & 31, ty = threadIdx.x >> 5;
  #pragma unroll
  for (int i = 0; i < 32; i += 8) {
    int k = kt + ty + i, c = ct + tx;
    tile[ty + i][tx] = (c < RR) ? in[(size_t)k * RR + c] : 0.f;
  }
  __syncthreads();
  #pragma unroll
  for (int i = 0; i < 32; i += 8) {
    int c = ct + ty + i;
    if (c < RR) out[(size_t)c * 1024 + kt + tx] = tile[tx][ty + i];
  }
}

// ====== gate-interleave biases: bg[n] = b[(n&3)*512 + (n>>2)] ======
__global__ __launch_bounds__(256) void k_bgi(const float* __restrict__ b0,
                                             const float* __restrict__ b1,
                                             float* __restrict__ b0g,
                                             float* __restrict__ b1g) {
  int idx = blockIdx.x * 256 + threadIdx.x;   // < 4096
  int n = idx & 2047;
  int src = (n & 3) * 512 + (n >> 2);
  if (idx < 2048) b0g[n] = b0[src];
  else            b1g[n] = b1[src];
}

// ============ big MFMA GEMM with LDS-staged full-line store epilogue ========
// C(MxN f32) = A(MxK bf16) @ BT(NxK)^T + bias. 128x128 tile, BK=64, 4 waves.
// mode 0: C[m*ldc+n]    mode 1: logits remap out[b*TT*VV + t*VV + n]
__global__ __launch_bounds__(256) void gemm_mfma(
    const short* __restrict__ A, int lda,
    const short* __restrict__ BT, int ldb,
    const float* __restrict__ bias,
    float* __restrict__ C, int ldc,
    int N, int K, int mode) {
  __shared__ __align__(16) char smem[36864];
  short (*As)[72] = (short(*)[72])smem;              // 128 x 72
  short (*Bs)[72] = (short(*)[72])(smem + 18432);    // 128 x 72
  float (*ZS)[132] = (float(*)[132])smem;            // 64 x 132 (aliases)
  const int tid = threadIdx.x;
  const int wv = tid >> 6, ln = tid & 63;
  const int m0 = blockIdx.y * 128, n0 = blockIdx.x * 128;
  const int mw = (wv & 1) * 64, nw = (wv >> 1) * 64;
  const int lrow = ln & 15, quad = ln >> 4, lk8 = quad * 8;

  f32x4 acc[4][4] = {};
  for (int k0 = 0; k0 < K; k0 += 64) {
    #pragma unroll
    for (int v = 0; v < 4; v++) {
      int f = v * 256 + tid, r = f >> 3, kk = (f & 7) * 8;
      *(uint4*)&As[r][kk] = *(const uint4*)&A[(size_t)(m0 + r) * lda + k0 + kk];
    }
    #pragma unroll
    for (int v = 0; v < 4; v++) {
      int f = v * 256 + tid, r = f >> 3, kk = (f & 7) * 8;
      int n = n0 + r;
      uint4 val{0, 0, 0, 0};
      if (n < N) val = *(const uint4*)&BT[(size_t)n * ldb + k0 + kk];
      *(uint4*)&Bs[r][kk] = val;
    }
    __syncthreads();
    #pragma unroll
    for (int ks = 0; ks < 64; ks += 32) {
      bf8 af[4], bf[4];
      #pragma unroll
      for (int i = 0; i < 4; i++)
        af[i] = *(const bf8*)&As[mw + i * 16 + lrow][ks + lk8];
      #pragma unroll
      for (int j = 0; j < 4; j++)
        bf[j] = *(const bf8*)&Bs[nw + j * 16 + lrow][ks + lk8];
      #pragma unroll
      for (int i = 0; i < 4; i++)
        #pragma unroll
        for (int j = 0; j < 4; j++)
          acc[i][j] = __builtin_amdgcn_mfma_f32_16x16x32_bf16(
              af[i], bf[j], acc[i][j], 0, 0, 0);
    }
    __syncthreads();
  }
  // epilogue: stage 64-row halves in LDS, write full-line float4 rows
  #pragma unroll
  for (int half = 0; half < 2; half++) {
    __syncthreads();
    if (mw == half * 64) {
      #pragma unroll
      for (int i = 0; i < 4; i++)
        #pragma unroll
        for (int j = 0; j < 4; j++)
          #pragma unroll
          for (int r = 0; r < 4; r++)
            ZS[i * 16 + quad * 4 + r][nw + j * 16 + lrow] = acc[i][j][r];
    }
    __syncthreads();
    int row = tid >> 2, ch = (tid & 3) * 32;
    int m = m0 + half * 64 + row;
    size_t base;
    if (mode == 0) base = (size_t)m * ldc;
    else {
      int t = m >> 7, b = m & 127;
      base = (size_t)b * (TT * VV) + (size_t)t * VV;
    }
    #pragma unroll
    for (int w = 0; w < 8; w++) {
      int n = n0 + ch + w * 4;
      if (n < N) {
        float4 v = *(float4*)&ZS[row][ch + w * 4];
        float4 bv = *(const float4*)&bias[n];
        v.x += bv.x; v.y += bv.y; v.z += bv.z; v.w += bv.w;
        *(float4*)&C[base + n] = v;
      }
    }
  }
}

// ============ K1: z0 GEMM (gate-interleaved) + LSTM0 activation ============
// A = PRV CCH h0 slot (stride 1536), B = W0hT_gi (2048x512). 32 blocks x 64 cols.
__global__ __launch_bounds__(256) void k_z0act(
    const short* __restrict__ Aprv, const short* __restrict__ BT,
    const float* __restrict__ X0t, float* __restrict__ C0,
    short* __restrict__ Ccur, float* __restrict__ HS) {
  __shared__ short As[128][72];
  __shared__ short Bs[64][72];
  const int tid = threadIdx.x, wv = tid >> 6, ln = tid & 63;
  const int n0 = blockIdx.x * 64;
  const int mw = (wv & 1) * 64, nw = (wv >> 1) * 32;
  const int lrow = ln & 15, quad = ln >> 4, lk8 = quad * 8;
  const int rL = tid >> 3, kA = (tid & 7) * 8;

  const short* Aptr = Aprv + (size_t)rL * 1536 + kA;
  const short* Bptr = BT + (size_t)(n0 + rL) * 512 + kA;
  uint4 pa[4], pb[2];
  #pragma unroll
  for (int v = 0; v < 4; v++) pa[v] = *(const uint4*)(Aptr + v * 32 * 1536);
  #pragma unroll
  for (int v = 0; v < 2; v++) pb[v] = *(const uint4*)(Bptr + v * 32 * 512);

  f32x4 acc[4][2] = {};
  for (int k0 = 0; k0 < 512; k0 += 64) {
    #pragma unroll
    for (int v = 0; v < 4; v++) *(uint4*)&As[v * 32 + rL][kA] = pa[v];
    #pragma unroll
    for (int v = 0; v < 2; v++) *(uint4*)&Bs[v * 32 + rL][kA] = pb[v];
    __syncthreads();
    if (k0 + 64 < 512) {
      #pragma unroll
      for (int v = 0; v < 4; v++)
        pa[v] = *(const uint4*)(Aptr + (k0 + 64) + v * 32 * 1536);
      #pragma unroll
      for (int v = 0; v < 2; v++)
        pb[v] = *(const uint4*)(Bptr + (k0 + 64) + v * 32 * 512);
    }
    #pragma unroll
    for (int ks = 0; ks < 64; ks += 32) {
      bf8 af[4], bf[2];
      #pragma unroll
      for (int i = 0; i < 4; i++)
        af[i] = *(const bf8*)&As[mw + i * 16 + lrow][ks + lk8];
      #pragma unroll
      for (int j = 0; j < 2; j++)
        bf[j] = *(const bf8*)&Bs[nw + j * 16 + lrow][ks + lk8];
      #pragma unroll
      for (int i = 0; i < 4; i++)
        #pragma unroll
        for (int j = 0; j < 2; j++)
          acc[i][j] = __builtin_amdgcn_mfma_f32_16x16x32_bf16(
              af[i], bf[j], acc[i][j], 0, 0, 0);
    }
    __syncthreads();
  }
  // fused activation: gates i,f,o,g live in adjacent lanes (n' = 4j+g)
  #pragma unroll
  for (int i = 0; i < 4; i++) {
    #pragma unroll
    for (int jf = 0; jf < 2; jf++) {
      int ncol = n0 + nw + jf * 16 + lrow;
      float z[4], zf_[4], zo_[4], zg_[4];
      #pragma unroll
      for (int r = 0; r < 4; r++) {
        int b = mw + i * 16 + quad * 4 + r;
        z[r] = acc[i][jf][r] + X0t[b * 2048 + ncol];
      }
      #pragma unroll
      for (int r = 0; r < 4; r++) {
        zf_[r] = __shfl_xor(z[r], 1);
        zo_[r] = __shfl_xor(z[r], 2);
        zg_[r] = __shfl_xor(z[r], 3);
      }
      if ((ln & 3) == 0) {
        int j = ncol >> 2;
        #pragma unroll
        for (int r = 0; r < 4; r++) {
          int b = mw + i * 16 + quad * 4 + r;
          float c  = C0[b * 512 + j];
          float cn = sigm(zf_[r]) * c + sigm(z[r]) * tanhf(zg_[r]);
          float hn = sigm(zo_[r]) * tanhf(cn);
          C0[b * 512 + j] = cn;
          Ccur[b * 1536 + j] = f2bf(hn);
          HS[b * 1024 + j] = hn;
          HS[b * 1024 + 512 + j] = cn;
        }
      }
    }
  }
}

// ============ K2: attention + softmax + context (1 block / b) ============
__global__ __launch_bounds__(256) void k_attn(
    const float* __restrict__ HS, const float* __restrict__ aWT,
    const float* __restrict__ ab, const float* __restrict__ feat,
    short* __restrict__ Ccur) {
  __shared__ float s0s[1024];
  __shared__ float sc[256];
  __shared__ float al[128];
  int b = blockIdx.x, tid = threadIdx.x;
  *(float4*)&s0s[tid * 4] = *(const float4*)&HS[b * 1024 + tid * 4];
  __syncthreads();
  if (tid < 200) {
    int r = tid >> 1, hf = tid & 1;
    const float* wr = aWT + r * 1024 + hf * 512;
    const float* sr = s0s + hf * 512;
    float a4 = 0.f;
    #pragma unroll 4
    for (int k = 0; k < 512; k += 4) {
      float4 w4 = *(const float4*)&wr[k];
      float4 s4 = *(const float4*)&sr[k];
      a4 += w4.x * s4.x + w4.y * s4.y + w4.z * s4.z + w4.w * s4.w;
    }
    sc[tid] = a4;
  }
  __syncthreads();
  if (tid < 128) al[tid] = -3.4e38f;
  if (tid < 100) al[tid] = sc[2 * tid] + sc[2 * tid + 1] + ab[tid];
  __syncthreads();
  if (tid < 128) sc[tid] = al[tid];
  __syncthreads();
  for (int off = 64; off; off >>= 1) {
    if (tid < off) sc[tid] = fmaxf(sc[tid], sc[tid + off]);
    __syncthreads();
  }
  float mx = sc[0];
  __syncthreads();
  if (tid < 128) { float e = (tid < 100) ? expf(al[tid] - mx) : 0.f; al[tid] = e; sc[tid] = e; }
  __syncthreads();
  for (int off = 64; off; off >>= 1) {
    if (tid < off) sc[tid] += sc[tid + off];
    __syncthreads();
  }
  float inv = 1.f / sc[0];
  __syncthreads();
  if (tid < 100) al[tid] *= inv;
  __syncthreads();
  int d = tid * 2;
  float s0 = 0.f, s1 = 0.f;
  for (int r = 0; r < RR; r++) {
    float a = al[r];
    float2 f2 = *(const float2*)&feat[((size_t)b * RR + r) * 512 + d];
    s0 += a * f2.x; s1 += a * f2.y;
  }
  short2 o;
  o.x = f2bf(s0); o.y = f2bf(s1);
  *(short2*)&Ccur[b * 1536 + 512 + d] = o;
}

// ============ K3: z1 GEMM (gate-interleaved, K=1536) + LSTM1 activation =====
__global__ __launch_bounds__(256) void k_z1act(
    const short* __restrict__ Acur, const short* __restrict__ BT,
    const float* __restrict__ b1g, float* __restrict__ C1,
    short* __restrict__ Cnxt, short* __restrict__ H1At) {
  __shared__ short As[128][72];
  __shared__ short Bs[64][72];
  const int tid = threadIdx.x, wv = tid >> 6, ln = tid & 63;
  const int n0 = blockIdx.x * 64;
  const int mw = (wv & 1) * 64, nw = (wv >> 1) * 32;
  const int lrow = ln & 15, quad = ln >> 4, lk8 = quad * 8;
  const int rL = tid >> 3, kA = (tid & 7) * 8;

  const short* Aptr = Acur + (size_t)rL * 1536 + kA;
  const short* Bptr = BT + (size_t)(n0 + rL) * 1536 + kA;
  uint4 pa[4], pb[2];
  #pragma unroll
  for (int v = 0; v < 4; v++) pa[v] = *(const uint4*)(Aptr + v * 32 * 1536);
  #pragma unroll
  for (int v = 0; v < 2; v++) pb[v] = *(const uint4*)(Bptr + v * 32 * 1536);

  f32x4 acc[4][2] = {};
  for (int k0 = 0; k0 < 1536; k0 += 64) {
    #pragma unroll
    for (int v = 0; v < 4; v++) *(uint4*)&As[v * 32 + rL][kA] = pa[v];
    #pragma unroll
    for (int v = 0; v < 2; v++) *(uint4*)&Bs[v * 32 + rL][kA] = pb[v];
    __syncthreads();
    if (k0 + 64 < 1536) {
      #pragma unroll
      for (int v = 0; v < 4; v++)
        pa[v] = *(const uint4*)(Aptr + (k0 + 64) + v * 32 * 1536);
      #pragma unroll
      for (int v = 0; v < 2; v++)
        pb[v] = *(const uint4*)(Bptr + (k0 + 64) + v * 32 * 1536);
    }
    #pragma unroll
    for (int ks = 0; ks < 64; ks += 32) {
      bf8 af[4], bf[2];
      #pragma unroll
      for (int i = 0; i < 4; i++)
        af[i] = *(const bf8*)&As[mw + i * 16 + lrow][ks + lk8];
      #pragma unroll
      for (int j = 0; j < 2; j++)
        bf[j] = *(const bf8*)&Bs[nw + j * 16 + lrow][ks + lk8];
      #pragma unroll
      for (int i = 0; i < 4; i++)
        #pragma unroll
        for (int j = 0; j < 2; j++)
          acc[i][j] = __builtin_amdgcn_mfma_f32_16x16x32_bf16(
              af[i], bf[j], acc[i][j], 0, 0, 0);
    }
    __syncthreads();
  }
  #pragma unroll
  for (int i = 0; i < 4; i++) {
    #pragma unroll
    for (int jf = 0; jf < 2; jf++) {
      int ncol = n0 + nw + jf * 16 + lrow;
      float bg = b1g[ncol];
      float z[4], zf_[4], zo_[4], zg_[4];
      #pragma unroll
      for (int r = 0; r < 4; r++) z[r] = acc[i][jf][r] + bg;
      #pragma unroll
      for (int r = 0; r < 4; r++) {
        zf_[r] = __shfl_xor(z[r], 1);
        zo_[r] = __shfl_xor(z[r], 2);
        zg_[r] = __shfl_xor(z[r], 3);
      }
      if ((ln & 3) == 0) {
        int j = ncol >> 2;
        #pragma unroll
        for (int r = 0; r < 4; r++) {
          int b = mw + i * 16 + quad * 4 + r;
          float c  = C1[b * 512 + j];
          float cn = sigm(zf_[r]) * c + sigm(z[r]) * tanhf(zg_[r]);
          float hn = sigm(zo_[r]) * tanhf(cn);
          C1[b * 512 + j] = cn;
          short hb = f2bf(hn);
          Cnxt[b * 1536 + 1024 + j] = hb;
          H1At[b * 512 + j] = hb;
        }
      }
    }
  }
}

// ============ final hidden state ============
__global__ __launch_bounds__(256) void k_final(
    const short* __restrict__ CCH0, const short* __restrict__ CCH1,
    const float* __restrict__ C0, const float* __restrict__ C1,
    float* __restrict__ out) {
  int idx = blockIdx.x * 256 + threadIdx.x;   // < 262144
  int s = idx >> 17, r = idx & 131071, b = r >> 10, j = r & 1023;
  float v;
  if (s == 0) v = (j < 512) ? bf2f(CCH0[b * 1536 + j])        : C0[b * 512 + j - 512];
  else        v = (j < 512) ? bf2f(CCH1[b * 1536 + 1024 + j]) : C1[b * 512 + j - 512];
  out[(size_t)BB * TT * VV + idx] = v;
}

extern "C" void kernel_launch(void* const* d_in, const int* in_sizes, int n_in,
                              void* d_out, int out_size, void* d_ws, size_t ws_size,
                              hipStream_t stream) {
  const int*   tok  = (const int*)  d_in[0];
  const float* feat = (const float*)d_in[1];
  const float* ihs  = (const float*)d_in[2];
  const float* emb  = (const float*)d_in[3];
  const float* W0   = (const float*)d_in[4];
  const float* b0   = (const float*)d_in[5];
  const float* W1   = (const float*)d_in[6];
  const float* b1   = (const float*)d_in[7];
  const float* aW   = (const float*)d_in[8];
  const float* ab   = (const float*)d_in[9];
  const float* oW   = (const float*)d_in[10];
  const float* ob   = (const float*)d_in[11];
  float* out = (float*)d_out;
  char*  w   = (char*)d_ws;

  // ws layout (bytes); XIN dead after X0 GEMM, aliases H1A. Total ~58.1 MB.
  short* XIN  = (short*)w;                    // 3200x1024 bf16
  short* H1A  = (short*)w;                    // 3200x512  bf16 (alias)
  float* X0   = (float*)(w + 6553600);        // 3200x2048 f32 (gate-interleaved)
  float* POOL = (float*)(w + 32768000);       // 128x512
  short* CCH0 = (short*)(w + 33030144);       // 128x1536 [h0|ctx|h1]
  short* CCH1 = (short*)(w + 33423360);       // 128x1536
  float* C0   = (float*)(w + 33816576);       // 128x512
  float* C1   = (float*)(w + 34078720);       // 128x512
  float* HS   = (float*)(w + 34340864);       // 128x1024 [h0'|c0'] f32
  short* W0xG = (short*)(w + 34865152);       // 2048x1024 bf16 gi
  short* W0hG = (short*)(w + 39059456);       // 2048x512  bf16 gi
  short* W1G  = (short*)(w + 41156608);       // 2048x1536 bf16 gi
  short* oWT  = (short*)(w + 47448064);       // 10000x512 bf16
  float* aWT  = (float*)(w + 57688064);       // 100x1024 f32
  float* b0g  = (float*)(w + 58097664);       // 2048
  float* b1g  = (float*)(w + 58105856);       // 2048

  k_init<<<1024, 256, 0, stream>>>(ihs, CCH0, CCH1, C0, C1);
  k_pool<<<256, 256, 0, stream>>>(feat, POOL);
  k_xin<<<12800, 256, 0, stream>>>(tok, emb, POOL, XIN);

  k_transpose<<<dim3(64, 32), 256, 0, stream>>>(W0, W0xG, 1024, 2048, 1);
  k_transpose<<<dim3(64, 16), 256, 0, stream>>>(W0 + 1024 * NG, W0hG, 512, 2048, 1);
  k_transpose<<<dim3(64, 48), 256, 0, stream>>>(W1, W1G, 1536, 2048, 1);
  k_transpose<<<dim3(313, 16), 256, 0, stream>>>(oW, oWT, 512, 10000, 0);
  k_transf<<<dim3(4, 32), 256, 0, stream>>>(aW, aWT);
  k_bgi<<<16, 256, 0, stream>>>(b0, b1, b0g, b1g);

  // X0 = Xin @ W0x_gi + b0_gi  (3200 x 2048, K=1024), gate-interleaved cols
  gemm_mfma<<<dim3(16, 25), 256, 0, stream>>>(
      XIN, 1024, W0xG, 1024, b0g, X0, NG, NG, 1024, 0);

  for (int t = 0; t < TT; t++) {
    short* CUR = (t & 1) ? CCH1 : CCH0;
    short* PRV = (t & 1) ? CCH0 : CCH1;
    k_z0act<<<32, 256, 0, stream>>>(PRV, W0hG, X0 + (size_t)t * BB * NG,
                                    C0, CUR, HS);
    k_attn<<<128, 256, 0, stream>>>(HS, aWT, ab, feat, CUR);
    k_z1act<<<32, 256, 0, stream>>>(CUR, W1G, b1g, C1, PRV,
                                    H1A + (size_t)t * BB * DD);
  }

  // logits = H1A @ out_W + out_b -> (B, T, V)
  gemm_mfma<<<dim3(79, 25), 256, 0, stream>>>(
      H1A, 512, oWT, 512, ob, out, VV, VV, 512, 1);
  k_final<<<1024, 256, 0, stream>>>(CCH0, CCH1, C0, C1, out);
}